// Round 7
// baseline (503.194 us; speedup 1.0000x reference)
//
#include <hip/hip_runtime.h>
#include <hip/hip_bf16.h>

// NeuralInelasticModel fused fwd + Jacobian, MFMA bf16, 16 samples/block.
// 65536 samples, NS=6, NI=8, H=256.
// out = [ydot(65536*6) | dy(65536*36) | de(65536*6) | dT(65536*6)]
// z2 (sign feeds m2 mask) via 3-term bf16 split (6 MFMA products) -> fp32-chain accuracy.
// m1 mask in registers (cross-lane via __shfl). LDS = 32768 B -> 5 blocks/CU.
// Phase D / ydot write directly to global (no LDS staging).

typedef unsigned short ushort_t;
typedef __attribute__((ext_vector_type(8))) short bf16x8;   // 8 bf16 = 4 VGPRs
typedef __attribute__((ext_vector_type(4))) float f32x4;

#define NSAMP (64 * 1024)
#define NG16 (NSAMP / 16)
#define OFF_YDOT 0
#define OFF_DY (NSAMP * 6)
#define OFF_DE (OFF_DY + NSAMP * 36)
#define OFF_DT (OFF_DE + NSAMP * 6)

// Weights repacked into MFMA B-fragment order:
// frag elem idx = ((nt*8 + kt)*64 + lane)*8 + jj,
// value = B[k = kt*32 + (lane>>4)*8 + jj][n = nt*16 + (lane&15)]
__device__ __align__(16) ushort_t g_w2T_hi[65536];   // z2 GEMM: B[k=j][n=h] = w2[h][j]
__device__ __align__(16) ushort_t g_w2T_mid[65536];
__device__ __align__(16) ushort_t g_w2T_lo[65536];
__device__ __align__(16) ushort_t g_w2B[65536];      // B GEMM:  B[k=h][n=j] = w2[h][j]
__device__ __align__(16) ushort_t g_w1e[4096];       // J GEMM:  B[k=j][n=kout] = w1[j][kout] (kout<8 else 0)
__device__ __align__(16) ushort_t g_w3b[1536];       // w3 bf16 row-major [6][256]

static __device__ __forceinline__ ushort_t f2bf(float f) {
    union { __hip_bfloat16 b; ushort_t u; } c;
    c.b = __float2bfloat16(f);
    return c.u;
}
static __device__ __forceinline__ float bf2f(ushort_t u) {
    union { ushort_t u; __hip_bfloat16 b; } c;
    c.u = u;
    return __bfloat162float(c.b);
}

__global__ void prep_kernel(const float* __restrict__ w1, const float* __restrict__ w2,
                            const float* __restrict__ w3) {
    const int gtid = blockIdx.x * blockDim.x + threadIdx.x;
    const int stride = gridDim.x * blockDim.x;
    for (int idx = gtid; idx < 65536; idx += stride) {
        const int nt = idx >> 12, kt = (idx >> 9) & 7, L = (idx >> 3) & 63, jj = idx & 7;
        const int n = nt * 16 + (L & 15);
        const int k = kt * 32 + ((L >> 4) & 3) * 8 + jj;
        const float vT = w2[n * 256 + k];          // w2T: B[k=j][n=h]
        const ushort_t hi = f2bf(vT);
        const float r1 = vT - bf2f(hi);
        const ushort_t mid = f2bf(r1);
        g_w2T_hi[idx]  = hi;
        g_w2T_mid[idx] = mid;
        g_w2T_lo[idx]  = f2bf(r1 - bf2f(mid));
        g_w2B[idx] = f2bf(w2[k * 256 + n]);        // w2B: B[k=h][n=j]
    }
    for (int idx = gtid; idx < 4096; idx += stride) {
        const int kt = idx >> 9, L = (idx >> 3) & 63, jj = idx & 7;
        const int kout = L & 15;
        const int j = kt * 32 + ((L >> 4) & 3) * 8 + jj;
        g_w1e[idx] = (kout < 8) ? f2bf(w1[j * 8 + kout]) : (ushort_t)0;
    }
    for (int idx = gtid; idx < 1536; idx += stride) g_w3b[idx] = f2bf(w3[idx]);
}

// LDS layout (32768 B -> 5 blocks/CU):
//   [0, 8192)      v1hi A-frag [8 kt][64 lane][8 jj] bf16 (phase B main loop).
//                    After mid-B barrier: v2B B-frag [8 kt][64][8] bf16
//                    (n-dim = sample 0..15; doubles as m2 mask).
//   [8192, 16384)  v1mid (phase B). Post-B: A2/Bm lower third.
//   [16384, 24576) v1lo  (phase B). Post-B: A2/Bm middle third.
//   [24576, 32768) unused pre-B.     Post-B: A2/Bm upper third.
//   A2/Bm: A-frag [3 mt][8 kt][64][8] bf16 (24576 B) @ 8192.
#define SMEM_BYTES 32768

__global__ __launch_bounds__(256, 5) void fused_kernel(
    const float* __restrict__ y, const float* __restrict__ erate,
    const float* __restrict__ Tin, const float* __restrict__ w1,
    const float* __restrict__ b1, const float* __restrict__ b2,
    const float* __restrict__ b3, float* __restrict__ out)
{
    __shared__ __align__(16) char smem[SMEM_BYTES];
    ushort_t* v1hi  = (ushort_t*)(smem + 0);
    ushort_t* v2B   = (ushort_t*)(smem + 0);      // alias: after mid-B barrier
    ushort_t* v1mid = (ushort_t*)(smem + 8192);
    ushort_t* v1lo  = (ushort_t*)(smem + 16384);
    ushort_t* A2    = (ushort_t*)(smem + 8192);   // alias: post-B, 24576 B (also Bm)

    const int tid  = threadIdx.x;
    const int lane = tid & 63;
    const int wave = tid >> 6;
    const int l15  = lane & 15;
    const int quad = lane >> 4;

    // per-thread weight regs for z1 (thread tid == hidden unit j)
    float w1r[8];
#pragma unroll
    for (int k = 0; k < 8; ++k) w1r[k] = w1[tid * 8 + k];
    const float b1r = b1[tid];
    float b2v[4];
#pragma unroll
    for (int n = 0; n < 4; ++n) b2v[n] = b2[(wave * 4 + n) * 16 + l15];

    const int g = blockIdx.x;
    const int s0 = g * 16;

    // ---- z1 (exact fp32; x via block-uniform scalar loads) + 3-way bf16 split ----
    unsigned int m1self = 0;  // bit s = (z1[s][tid] > 0)
    {
        const int ktw = tid >> 5, qd = (tid >> 3) & 3, jj = tid & 7;
#pragma unroll 4
        for (int s = 0; s < 16; ++s) {
            float z = b1r;
#pragma unroll
            for (int k = 0; k < 6; ++k) z = fmaf(w1r[k], y[(s0 + s) * 6 + k], z);
            z = fmaf(w1r[6], erate[s0 + s], z);
            z = fmaf(w1r[7], Tin[s0 + s], z);
            const float v = fmaxf(z, 0.0f);
            m1self |= (v > 0.0f ? 1u : 0u) << s;
            const ushort_t hi = f2bf(v);
            const float r1 = v - bf2f(hi);
            const ushort_t mid = f2bf(r1);
            const int e = ((ktw * 64 + (s | (qd << 4))) * 8 + jj);
            v1hi[e]  = hi;
            v1mid[e] = mid;
            v1lo[e]  = f2bf(r1 - bf2f(mid));
        }
    }
    __syncthreads();  // (1) splits visible

    // ---- phase B: z2 = v1 @ w2^T, 3-way split (6 MFMAs), M=16(s) N=256(h) K=256(j) ----
    {
        f32x4 cz[4];
#pragma unroll
        for (int n = 0; n < 4; ++n) cz[n] = (f32x4){0, 0, 0, 0};
#pragma unroll 2
        for (int kt = 0; kt < 8; ++kt) {
            const int aoff = (kt * 64 + lane) * 8;
            bf16x8 ahi = *(const bf16x8*)&v1hi[aoff];
            bf16x8 ami = *(const bf16x8*)&v1mid[aoff];
            bf16x8 alo = *(const bf16x8*)&v1lo[aoff];
#pragma unroll
            for (int n = 0; n < 4; ++n) {
                const int bidx = (((wave * 4 + n) * 8 + kt) * 64 + lane) * 8;
                bf16x8 bh = *(const bf16x8*)&g_w2T_hi[bidx];
                bf16x8 bm = *(const bf16x8*)&g_w2T_mid[bidx];
                bf16x8 bl = *(const bf16x8*)&g_w2T_lo[bidx];
                cz[n] = __builtin_amdgcn_mfma_f32_16x16x32_bf16(alo, bh, cz[n], 0, 0, 0);
                cz[n] = __builtin_amdgcn_mfma_f32_16x16x32_bf16(ami, bm, cz[n], 0, 0, 0);
                cz[n] = __builtin_amdgcn_mfma_f32_16x16x32_bf16(ahi, bl, cz[n], 0, 0, 0);
                cz[n] = __builtin_amdgcn_mfma_f32_16x16x32_bf16(ami, bh, cz[n], 0, 0, 0);
                cz[n] = __builtin_amdgcn_mfma_f32_16x16x32_bf16(ahi, bm, cz[n], 0, 0, 0);
                cz[n] = __builtin_amdgcn_mfma_f32_16x16x32_bf16(ahi, bh, cz[n], 0, 0, 0);
            }
        }
        __syncthreads();  // (2) all v1hi/mid/lo reads done -> v2B may overwrite v1hi

        // epilogue: v2 = relu(z2 + b2) -> v2B (B-frag layout, n=sample; doubles as m2)
#pragma unroll
        for (int n = 0; n < 4; ++n) {
            const int h = (wave * 4 + n) * 16 + l15;
            const int ktd = h >> 5, qd = (h >> 3) & 3, jj = h & 7;
#pragma unroll
            for (int r = 0; r < 4; ++r) {
                const int s = quad * 4 + r;  // C layout: row = quad*4 + reg
                const float v2 = fmaxf(cz[n][r] + b2v[n], 0.0f);
                v2B[(ktd * 64 + (s | (qd << 4))) * 8 + jj] = f2bf(v2);
            }
        }
    }
    __syncthreads();  // (3) v2B visible

    // ---- chunks of 8 samples: A2 build, C (B=A2@w2), Bm, D (J=Bm@w1e, direct stores) ----
#pragma unroll 1
    for (int c = 0; c < 2; ++c) {
        // build A2[m = sl*6+i][h] = m2[sg][h] ? w3[i][h] : 0, A-frag layout (192 threads)
        if (tid < 192) {
            const int mt = tid >> 6;
            const int m = mt * 16 + l15;
            const int sl = m / 6, i = m - sl * 6;
            const int sg = c * 8 + sl;
#pragma unroll 1
            for (int kt = 0; kt < 8; ++kt) {
                bf16x8 vv = *(const bf16x8*)&v2B[(kt * 64 + (sg | (quad << 4))) * 8];
                bf16x8 wv = *(const bf16x8*)&g_w3b[i * 256 + kt * 32 + quad * 8];
                bf16x8 o;
#pragma unroll
                for (int e = 0; e < 8; ++e)
                    o[e] = ((ushort_t)vv[e] != 0) ? wv[e] : (short)0;
                *(bf16x8*)&A2[((mt * 8 + kt) * 64 + lane) * 8] = o;
            }
        }
        __syncthreads();  // (4) A2 visible

        // phase C: B = A2 @ w2 (M=48 N=256 K=256); wave 3 also does the ydot tile
        f32x4 cc[3][4], cy[3];
#pragma unroll
        for (int mt = 0; mt < 3; ++mt) {
#pragma unroll
            for (int n = 0; n < 4; ++n) cc[mt][n] = (f32x4){0, 0, 0, 0};
            cy[mt] = (f32x4){0, 0, 0, 0};
        }
#pragma unroll 2
        for (int kt = 0; kt < 8; ++kt) {
            bf16x8 a[3];
#pragma unroll
            for (int mt = 0; mt < 3; ++mt)
                a[mt] = *(const bf16x8*)&A2[((mt * 8 + kt) * 64 + lane) * 8];
#pragma unroll
            for (int n = 0; n < 4; ++n) {
                bf16x8 b = *(const bf16x8*)&g_w2B[(((wave * 4 + n) * 8 + kt) * 64 + lane) * 8];
#pragma unroll
                for (int mt = 0; mt < 3; ++mt)
                    cc[mt][n] = __builtin_amdgcn_mfma_f32_16x16x32_bf16(a[mt], b, cc[mt][n], 0, 0, 0);
            }
            if (wave == 3) {
                bf16x8 bv = *(const bf16x8*)&v2B[(kt * 64 + lane) * 8];
#pragma unroll
                for (int mt = 0; mt < 3; ++mt)
                    cy[mt] = __builtin_amdgcn_mfma_f32_16x16x32_bf16(a[mt], bv, cy[mt], 0, 0, 0);
            }
        }
        __syncthreads();  // (5) all A2 reads complete before Bm overwrites

        // Bm = (B .* m1) -> bf16 back into A2 region (A-frag layout).
        // m1 via in-wave shuffle: column j's mask is held by lane n*16+l15.
#pragma unroll
        for (int n = 0; n < 4; ++n) {
            const unsigned int mcol = (unsigned int)__shfl((int)m1self, n * 16 + l15, 64);
            const int j = (wave * 4 + n) * 16 + l15;  // C layout: col = lane&15
            const int ktd = j >> 5, qd = (j >> 3) & 3, jjd = j & 7;
#pragma unroll
            for (int mt = 0; mt < 3; ++mt) {
#pragma unroll
                for (int r = 0; r < 4; ++r) {
                    const int m = mt * 16 + quad * 4 + r;  // C layout: row = quad*4+reg
                    const int sg = c * 8 + m / 6;
                    const ushort_t bm =
                        ((mcol >> sg) & 1u) ? f2bf(cc[mt][n][r]) : (ushort_t)0;
                    A2[((mt * 8 + ktd) * 64 + ((m & 15) | (qd << 4))) * 8 + jjd] = bm;
                }
            }
        }
        __syncthreads();  // (6) Bm visible

        // phase D: J = Bm @ w1e (M=48 N=16 K=256); waves 0-2, direct global stores.
        // Wave 3 stores ydot from the extra tile's diagonal.
        if (wave < 3) {
            f32x4 dc = {0, 0, 0, 0};
#pragma unroll 1
            for (int kt = 0; kt < 8; ++kt) {
                bf16x8 a = *(const bf16x8*)&A2[((wave * 8 + kt) * 64 + lane) * 8];
                bf16x8 b = *(const bf16x8*)&g_w1e[(kt * 64 + lane) * 8];
                dc = __builtin_amdgcn_mfma_f32_16x16x32_bf16(a, b, dc, 0, 0, 0);
            }
            if (l15 < 8) {
                const int kout = l15;
#pragma unroll
                for (int r = 0; r < 4; ++r) {
                    const int m = wave * 16 + quad * 4 + r;
                    const int sl = m / 6, i = m - sl * 6;
                    const int sg = s0 + c * 8 + sl;
                    if (kout < 6)      out[OFF_DY + sg * 36 + i * 6 + kout] = dc[r];
                    else if (kout == 6) out[OFF_DE + sg * 6 + i] = dc[r];
                    else                out[OFF_DT + sg * 6 + i] = dc[r];
                }
            }
        } else {  // ydot: diag of extra tile (col l15 = global sample-in-group idx)
#pragma unroll
            for (int mt = 0; mt < 3; ++mt) {
#pragma unroll
                for (int r = 0; r < 4; ++r) {
                    const int m = mt * 16 + quad * 4 + r;
                    const int sl = m / 6, i = m - sl * 6;
                    if (l15 == c * 8 + sl)
                        out[OFF_YDOT + (s0 + c * 8 + sl) * 6 + i] = cy[mt][r] + b3[i];
                }
            }
        }
        __syncthreads();  // (7) D's Bm reads done -> next chunk's A2 build may write
    }
}

extern "C" void kernel_launch(void* const* d_in, const int* in_sizes, int n_in,
                              void* d_out, int out_size, void* d_ws, size_t ws_size,
                              hipStream_t stream) {
    // setup_inputs order: t(0,unused), y(1), erate(2), T(3), w1(4), w2(5), w3(6), b1(7), b2(8), b3(9)
    const float* y     = (const float*)d_in[1];
    const float* erate = (const float*)d_in[2];
    const float* Tin   = (const float*)d_in[3];
    const float* w1    = (const float*)d_in[4];
    const float* w2    = (const float*)d_in[5];
    const float* w3    = (const float*)d_in[6];
    const float* b1    = (const float*)d_in[7];
    const float* b2    = (const float*)d_in[8];
    const float* b3    = (const float*)d_in[9];
    float* out = (float*)d_out;

    prep_kernel<<<dim3(64), dim3(256), 0, stream>>>(w1, w2, w3);
    fused_kernel<<<dim3(NG16), dim3(256), 0, stream>>>(
        y, erate, Tin, w1, b1, b2, b3, out);
}

// Round 8
// 398.657 us; speedup vs baseline: 1.2622x; 1.2622x over previous
//
#include <hip/hip_runtime.h>
#include <hip/hip_bf16.h>

// NeuralInelasticModel fused fwd + Jacobian, MFMA bf16, 16 samples/block.
// 65536 samples, NS=6, NI=8, H=256.
// out = [ydot(65536*6) | dy(65536*36) | de(65536*6) | dT(65536*6)]
// z2 (sign feeds m2 mask) via 3-term bf16 split (6 MFMA products) -> fp32-chain accuracy.
// m1 mask in registers (cross-lane via __shfl). R5 structure (350 us): xs LDS staging,
// shared A2 build, LDS-staged coalesced outputs, 40960 B LDS / 4 blocks/CU.

typedef unsigned short ushort_t;
typedef __attribute__((ext_vector_type(8))) short bf16x8;   // 8 bf16 = 4 VGPRs
typedef __attribute__((ext_vector_type(4))) float f32x4;

#define NSAMP (64 * 1024)
#define NG16 (NSAMP / 16)
#define OFF_YDOT 0
#define OFF_DY (NSAMP * 6)
#define OFF_DE (OFF_DY + NSAMP * 36)
#define OFF_DT (OFF_DE + NSAMP * 6)

// Weights repacked into MFMA B-fragment order:
// frag elem idx = ((nt*8 + kt)*64 + lane)*8 + jj,
// value = B[k = kt*32 + (lane>>4)*8 + jj][n = nt*16 + (lane&15)]
__device__ __align__(16) ushort_t g_w2T_hi[65536];   // z2 GEMM: B[k=j][n=h] = w2[h][j]
__device__ __align__(16) ushort_t g_w2T_mid[65536];
__device__ __align__(16) ushort_t g_w2T_lo[65536];
__device__ __align__(16) ushort_t g_w2B[65536];      // B GEMM:  B[k=h][n=j] = w2[h][j]
__device__ __align__(16) ushort_t g_w1e[4096];       // J GEMM:  B[k=j][n=kout] = w1[j][kout] (kout<8 else 0)
__device__ __align__(16) ushort_t g_w3b[1536];       // w3 bf16 row-major [6][256]

static __device__ __forceinline__ ushort_t f2bf(float f) {
    union { __hip_bfloat16 b; ushort_t u; } c;
    c.b = __float2bfloat16(f);
    return c.u;
}
static __device__ __forceinline__ float bf2f(ushort_t u) {
    union { ushort_t u; __hip_bfloat16 b; } c;
    c.u = u;
    return __bfloat162float(c.b);
}

__global__ void prep_kernel(const float* __restrict__ w1, const float* __restrict__ w2,
                            const float* __restrict__ w3) {
    const int gtid = blockIdx.x * blockDim.x + threadIdx.x;
    const int stride = gridDim.x * blockDim.x;
    for (int idx = gtid; idx < 65536; idx += stride) {
        const int nt = idx >> 12, kt = (idx >> 9) & 7, L = (idx >> 3) & 63, jj = idx & 7;
        const int n = nt * 16 + (L & 15);
        const int k = kt * 32 + ((L >> 4) & 3) * 8 + jj;
        const float vT = w2[n * 256 + k];          // w2T: B[k=j][n=h]
        const ushort_t hi = f2bf(vT);
        const float r1 = vT - bf2f(hi);
        const ushort_t mid = f2bf(r1);
        g_w2T_hi[idx]  = hi;
        g_w2T_mid[idx] = mid;
        g_w2T_lo[idx]  = f2bf(r1 - bf2f(mid));
        g_w2B[idx] = f2bf(w2[k * 256 + n]);        // w2B: B[k=h][n=j]
    }
    for (int idx = gtid; idx < 4096; idx += stride) {
        const int kt = idx >> 9, L = (idx >> 3) & 63, jj = idx & 7;
        const int kout = L & 15;
        const int j = kt * 32 + ((L >> 4) & 3) * 8 + jj;
        g_w1e[idx] = (kout < 8) ? f2bf(w1[j * 8 + kout]) : (ushort_t)0;
    }
    for (int idx = gtid; idx < 1536; idx += stride) g_w3b[idx] = f2bf(w3[idx]);
}

// LDS layout (40960 B -> 4 blocks/CU):
//   [0, 8192)      v1hi A-frag [8 kt][64 lane][8 jj] bf16. Dead after phase B.
//                    Post-B alias: Jsh [48][8] f32 @0 (1536), ydsh[48] f32 @1536.
//   [8192, 32768)  phase-B: v1mid @8192 (8192), v1lo @16384 (8192), xs @24576 (512).
//                    Post-B alias: A2/Bm A-frag [3 mt][8 kt][64][8] bf16 (24576).
//   [32768, 40960) v2B B-frag [8 kt][64][8] bf16; n-dim = sample 0..15; doubles as m2 mask.
#define SMEM_BYTES 40960

__global__ __launch_bounds__(256, 4) void fused_kernel(
    const float* __restrict__ y, const float* __restrict__ erate,
    const float* __restrict__ Tin, const float* __restrict__ w1,
    const float* __restrict__ b1, const float* __restrict__ b2,
    const float* __restrict__ b3, float* __restrict__ out)
{
    __shared__ __align__(16) char smem[SMEM_BYTES];
    ushort_t* v1hi  = (ushort_t*)(smem + 0);
    float*    Jsh   = (float*)(smem + 0);
    float*    ydsh  = (float*)(smem + 1536);
    ushort_t* v1mid = (ushort_t*)(smem + 8192);
    ushort_t* v1lo  = (ushort_t*)(smem + 16384);
    ushort_t* A2    = (ushort_t*)(smem + 8192);
    float*    xs    = (float*)(smem + 24576);
    ushort_t* v2B   = (ushort_t*)(smem + 32768);

    const int tid  = threadIdx.x;
    const int lane = tid & 63;
    const int wave = tid >> 6;
    const int l15  = lane & 15;
    const int quad = lane >> 4;

    // per-thread weight regs for z1 (thread tid == hidden unit j)
    float w1r[8];
#pragma unroll
    for (int k = 0; k < 8; ++k) w1r[k] = w1[tid * 8 + k];
    const float b1r = b1[tid];
    float b2v[4];
#pragma unroll
    for (int n = 0; n < 4; ++n) b2v[n] = b2[(wave * 4 + n) * 16 + l15];

    const int g = blockIdx.x;
    const int s0 = g * 16;

    // ---- stage x for 16 samples (vector loads -> LDS) ----
    if (tid < 128) {
        const int s = tid >> 3, k = tid & 7;
        float v;
        if (k < 6)       v = y[(s0 + s) * 6 + k];
        else if (k == 6) v = erate[s0 + s];
        else             v = Tin[s0 + s];
        xs[s * 8 + k] = v;
    }
    __syncthreads();

    // ---- z1 (exact fp32) + 3-way bf16 split of v1 (A-frag layout) + register m1 mask ----
    unsigned int m1self = 0;  // bit s = (z1[s][tid] > 0)
    {
        const int ktw = tid >> 5, qd = (tid >> 3) & 3, jj = tid & 7;
#pragma unroll 4
        for (int s = 0; s < 16; ++s) {
            float z = b1r;
#pragma unroll
            for (int k = 0; k < 8; ++k) z = fmaf(w1r[k], xs[s * 8 + k], z);
            const float v = fmaxf(z, 0.0f);
            m1self |= (v > 0.0f ? 1u : 0u) << s;
            const ushort_t hi = f2bf(v);
            const float r1 = v - bf2f(hi);
            const ushort_t mid = f2bf(r1);
            const int e = ((ktw * 64 + (s | (qd << 4))) * 8 + jj);
            v1hi[e]  = hi;
            v1mid[e] = mid;
            v1lo[e]  = f2bf(r1 - bf2f(mid));
        }
    }
    __syncthreads();  // (1) splits visible

    // ---- phase B: z2 = v1 @ w2^T, 3-way split (6 MFMAs), M=16(s) N=256(h) K=256(j) ----
    {
        f32x4 cz[4];
#pragma unroll
        for (int n = 0; n < 4; ++n) cz[n] = (f32x4){0, 0, 0, 0};
#pragma unroll 4
        for (int kt = 0; kt < 8; ++kt) {
            const int aoff = (kt * 64 + lane) * 8;
            bf16x8 ahi = *(const bf16x8*)&v1hi[aoff];
            bf16x8 ami = *(const bf16x8*)&v1mid[aoff];
            bf16x8 alo = *(const bf16x8*)&v1lo[aoff];
#pragma unroll
            for (int n = 0; n < 4; ++n) {
                const int bidx = (((wave * 4 + n) * 8 + kt) * 64 + lane) * 8;
                bf16x8 bh = *(const bf16x8*)&g_w2T_hi[bidx];
                bf16x8 bm = *(const bf16x8*)&g_w2T_mid[bidx];
                bf16x8 bl = *(const bf16x8*)&g_w2T_lo[bidx];
                cz[n] = __builtin_amdgcn_mfma_f32_16x16x32_bf16(alo, bh, cz[n], 0, 0, 0);
                cz[n] = __builtin_amdgcn_mfma_f32_16x16x32_bf16(ami, bm, cz[n], 0, 0, 0);
                cz[n] = __builtin_amdgcn_mfma_f32_16x16x32_bf16(ahi, bl, cz[n], 0, 0, 0);
                cz[n] = __builtin_amdgcn_mfma_f32_16x16x32_bf16(ami, bh, cz[n], 0, 0, 0);
                cz[n] = __builtin_amdgcn_mfma_f32_16x16x32_bf16(ahi, bm, cz[n], 0, 0, 0);
                cz[n] = __builtin_amdgcn_mfma_f32_16x16x32_bf16(ahi, bh, cz[n], 0, 0, 0);
            }
        }
        // epilogue: v2 = relu(z2 + b2) -> v2B (B-frag layout, n=sample; doubles as m2)
#pragma unroll
        for (int n = 0; n < 4; ++n) {
            const int h = (wave * 4 + n) * 16 + l15;
            const int ktd = h >> 5, qd = (h >> 3) & 3, jj = h & 7;
#pragma unroll
            for (int r = 0; r < 4; ++r) {
                const int s = quad * 4 + r;  // C layout: row = quad*4 + reg
                const float v2 = fmaxf(cz[n][r] + b2v[n], 0.0f);
                v2B[(ktd * 64 + (s | (qd << 4))) * 8 + jj] = f2bf(v2);
            }
        }
    }
    __syncthreads();  // (2) v2B visible; also: all split reads done -> A2 region writable

    // ---- chunks of 8 samples: A2 build, C (B=A2@w2), Bm, D (J=Bm@w1e), out ----
#pragma unroll 1
    for (int c = 0; c < 2; ++c) {
        // build A2[m = sl*6+i][h] = m2[sg][h] ? w3[i][h] : 0, A-frag layout (192 threads)
        if (tid < 192) {
            const int mt = tid >> 6;
            const int m = mt * 16 + l15;
            const int sl = m / 6, i = m - sl * 6;
            const int sg = c * 8 + sl;
#pragma unroll 2
            for (int kt = 0; kt < 8; ++kt) {
                bf16x8 vv = *(const bf16x8*)&v2B[(kt * 64 + (sg | (quad << 4))) * 8];
                bf16x8 wv = *(const bf16x8*)&g_w3b[i * 256 + kt * 32 + quad * 8];
                bf16x8 o;
#pragma unroll
                for (int e = 0; e < 8; ++e)
                    o[e] = ((ushort_t)vv[e] != 0) ? wv[e] : (short)0;
                *(bf16x8*)&A2[((mt * 8 + kt) * 64 + lane) * 8] = o;
            }
        }
        __syncthreads();  // (3) A2 visible

        // phase C: B = A2 @ w2 (M=48 N=256 K=256); wave 3 also does the ydot tile
        f32x4 cc[3][4], cy[3];
#pragma unroll
        for (int mt = 0; mt < 3; ++mt) {
#pragma unroll
            for (int n = 0; n < 4; ++n) cc[mt][n] = (f32x4){0, 0, 0, 0};
            cy[mt] = (f32x4){0, 0, 0, 0};
        }
#pragma unroll 2
        for (int kt = 0; kt < 8; ++kt) {
            bf16x8 a[3];
#pragma unroll
            for (int mt = 0; mt < 3; ++mt)
                a[mt] = *(const bf16x8*)&A2[((mt * 8 + kt) * 64 + lane) * 8];
#pragma unroll
            for (int n = 0; n < 4; ++n) {
                bf16x8 b = *(const bf16x8*)&g_w2B[(((wave * 4 + n) * 8 + kt) * 64 + lane) * 8];
#pragma unroll
                for (int mt = 0; mt < 3; ++mt)
                    cc[mt][n] = __builtin_amdgcn_mfma_f32_16x16x32_bf16(a[mt], b, cc[mt][n], 0, 0, 0);
            }
            if (wave == 3) {
                bf16x8 bv = *(const bf16x8*)&v2B[(kt * 64 + lane) * 8];
#pragma unroll
                for (int mt = 0; mt < 3; ++mt)
                    cy[mt] = __builtin_amdgcn_mfma_f32_16x16x32_bf16(a[mt], bv, cy[mt], 0, 0, 0);
            }
        }
        __syncthreads();  // (4) all A2 reads complete before Bm overwrites

        // Bm = (B .* m1) -> bf16 back into A2 region (A-frag layout).
        // m1 via in-wave shuffle: column j's mask is held by lane n*16+l15.
#pragma unroll
        for (int n = 0; n < 4; ++n) {
            const unsigned int mcol = (unsigned int)__shfl((int)m1self, n * 16 + l15, 64);
            const int j = (wave * 4 + n) * 16 + l15;  // C layout: col = lane&15
            const int ktd = j >> 5, qd = (j >> 3) & 3, jjd = j & 7;
#pragma unroll
            for (int mt = 0; mt < 3; ++mt) {
#pragma unroll
                for (int r = 0; r < 4; ++r) {
                    const int m = mt * 16 + quad * 4 + r;  // C layout: row = quad*4+reg
                    const int sg = c * 8 + m / 6;
                    const ushort_t bm =
                        ((mcol >> sg) & 1u) ? f2bf(cc[mt][n][r]) : (ushort_t)0;
                    A2[((mt * 8 + ktd) * 64 + ((m & 15) | (qd << 4))) * 8 + jjd] = bm;
                }
            }
        }
        __syncthreads();  // (5) Bm visible (also orders prev-chunk out-reads vs Jsh writes)

        // phase D: J = Bm @ w1e (M=48 N=16 K=256); waves 0-2. Wave 3 writes ydot.
        if (wave < 3) {
            f32x4 dc = {0, 0, 0, 0};
#pragma unroll 2
            for (int kt = 0; kt < 8; ++kt) {
                bf16x8 a = *(const bf16x8*)&A2[((wave * 8 + kt) * 64 + lane) * 8];
                bf16x8 b = *(const bf16x8*)&g_w1e[(kt * 64 + lane) * 8];
                dc = __builtin_amdgcn_mfma_f32_16x16x32_bf16(a, b, dc, 0, 0, 0);
            }
            if (l15 < 8) {
#pragma unroll
                for (int r = 0; r < 4; ++r) {
                    const int m = wave * 16 + quad * 4 + r;
                    Jsh[m * 8 + l15] = dc[r];
                }
            }
        } else {  // ydot from the diag of the extra tile (col = global sample idx)
#pragma unroll
            for (int mt = 0; mt < 3; ++mt) {
#pragma unroll
                for (int r = 0; r < 4; ++r) {
                    const int m = mt * 16 + quad * 4 + r;
                    const int sl = m / 6, i = m - sl * 6;
                    if (l15 == c * 8 + sl) ydsh[m] = cy[mt][r] + b3[i];
                }
            }
        }
        __syncthreads();  // (6) Jsh/ydsh visible (also: all Bm reads done -> next chunk may overwrite)

        // coalesced output for this chunk's 8 samples
        {
            const int s0c = s0 + c * 8;
            const long base6 = (long)s0c * 6;
            {
                const int u = tid;  // dy dwords 0..255
                const int s = u / 36, rem = u - s * 36, ii = rem / 6, jy = rem - ii * 6;
                out[OFF_DY + (long)s0c * 36 + u] = Jsh[(s * 6 + ii) * 8 + jy];
            }
            if (tid < 32) {  // dy dwords 256..287
                const int u = 256 + tid;
                const int s = u / 36, rem = u - s * 36, ii = rem / 6, jy = rem - ii * 6;
                out[OFF_DY + (long)s0c * 36 + u] = Jsh[(s * 6 + ii) * 8 + jy];
            }
            if (tid < 48) out[OFF_YDOT + base6 + tid] = ydsh[tid];
            const int t2 = tid - 64;
            if (t2 >= 0 && t2 < 48) out[OFF_DE + base6 + t2] = Jsh[t2 * 8 + 6];
            const int t3 = tid - 128;
            if (t3 >= 0 && t3 < 48) out[OFF_DT + base6 + t3] = Jsh[t3 * 8 + 7];
        }
    }
}

extern "C" void kernel_launch(void* const* d_in, const int* in_sizes, int n_in,
                              void* d_out, int out_size, void* d_ws, size_t ws_size,
                              hipStream_t stream) {
    // setup_inputs order: t(0,unused), y(1), erate(2), T(3), w1(4), w2(5), w3(6), b1(7), b2(8), b3(9)
    const float* y     = (const float*)d_in[1];
    const float* erate = (const float*)d_in[2];
    const float* Tin   = (const float*)d_in[3];
    const float* w1    = (const float*)d_in[4];
    const float* w2    = (const float*)d_in[5];
    const float* w3    = (const float*)d_in[6];
    const float* b1    = (const float*)d_in[7];
    const float* b2    = (const float*)d_in[8];
    const float* b3    = (const float*)d_in[9];
    float* out = (float*)d_out;

    prep_kernel<<<dim3(64), dim3(256), 0, stream>>>(w1, w2, w3);
    fused_kernel<<<dim3(NG16), dim3(256), 0, stream>>>(
        y, erate, Tin, w1, b1, b2, b3, out);
}